// Round 14
// baseline (401.292 us; speedup 1.0000x reference)
//
#include <hip/hip_runtime.h>

#define N_NODES   100000
#define N_EDGES   800000
#define N_ETYPES  5
#define IN_DIM    23
#define HID_DIM   128
#define OUT_DIM   64
#define NUM_GRAPHS 64
#define NBKT      391                   // ceil(100000/256) dst buckets of 256 nodes
#define PBLK      125                   // partition blocks per etype
#define CHUNK     6400                  // 125*6400 = 800000 edges per etype
#define NB_E      (N_ETYPES*NBKT)       // 1955 (e,bucket) pairs
#define BKT_CAP   3072                  // slot size per (e,bucket); mean 2048 + 22 sigma
#define ASTR      136                   // gemm2-phase LDS stride: conflict-free b128 frags
#define A1STR     40                    // gemm1-phase LDS stride: 2-way only (free)

// NOTE (measured r3): bulk LDS float atomics ~3.5 cyc/lane on gfx950 — register acc only.
// NOTE (measured r6): unpadded bf16 LDS tiles -> 16-way conflicts on MFMA ds_read_b128.
// NOTE (measured r7-r11): random row-gather over a table >4MB/XCD has a compulsory
// L2-miss floor of 8 XCDs x touched-lines; tuning can't reduce it.
// NOTE (measured r12): pool-commute spool over 256 B H1 rows octupled edge payload — 4x
// regression. Pool-commute only pays if spooled rows are NARROWER than gathered rows.
// NOTE (measured r5/r10/r13): row-gather kernels are bound by the vector-memory REQUEST
// rate: ~50k wave-requests/us device-wide (~12 cyc/request/CU), independent of row
// bytes (32 B and 64 B rows identical). Floor per gather stage = edge_count / 50k.
// r14: agg1's 4.5M-request gather fused into gemm12's A-tile staging (AGG1B deleted).

__device__ __forceinline__ unsigned short f2bf(float x) {
    unsigned u = __float_as_uint(x);
    unsigned r = (u + 0x7FFFu + ((u >> 16) & 1u)) >> 16;   // RNE
    return (unsigned short)r;
}
__device__ __forceinline__ float bf2f(unsigned short h) {
    return __uint_as_float(((unsigned)h) << 16);
}

typedef __attribute__((ext_vector_type(8))) short bf16x8;
typedef __attribute__((ext_vector_type(4))) float f32x4;
typedef __attribute__((ext_vector_type(2))) float f32x2;

// ---------------- feat -> fp8-e4m3 table, 32-dim rows (32 B, table 3.2 MB) -------
__global__ __launch_bounds__(256) void cvt_feat_k(const float* __restrict__ feat,
                                                  unsigned short* __restrict__ fb8) {
    int i = blockIdx.x * 256 + threadIdx.x;
    if (i < N_NODES * 16) {
        int n = i >> 4, p = i & 15;
        int d0 = p * 2, d1 = d0 + 1;
        float f0 = (d0 < IN_DIM) ? feat[n * IN_DIM + d0] : 0.f;
        float f1 = (d1 < IN_DIM) ? feat[n * IN_DIM + d1] : 0.f;
        int pk = __builtin_amdgcn_cvt_pk_fp8_f32(f0, f1, 0, false);
        fb8[i] = (unsigned short)(pk & 0xFFFF);
    }
}

// ---------------- weight prep: W1^T bf16 (k-pad 32), W2^T bf16, b1 sum ----------
__global__ __launch_bounds__(256) void cvt_w_k(const float* __restrict__ W1,
                                               const float* __restrict__ b1,
                                               const float* __restrict__ W2,
                                               unsigned short* __restrict__ w1tb,
                                               unsigned short* __restrict__ w2tb,
                                               float* __restrict__ b1s) {
    int i = blockIdx.x * 256 + threadIdx.x;
    if (i < N_ETYPES * OUT_DIM * HID_DIM) {
        int e = i / (OUT_DIM * HID_DIM);
        int r = i - e * (OUT_DIM * HID_DIM);
        int n = r >> 7, k = r & 127;
        w2tb[i] = f2bf(W2[(e * HID_DIM + k) * OUT_DIM + n]);
    }
    if (i < N_ETYPES * HID_DIM * 32) {
        int e = i / (HID_DIM * 32);
        int r = i - e * (HID_DIM * 32);
        int n = r >> 5, k = r & 31;
        w1tb[i] = (k < IN_DIM) ? f2bf(W1[e * IN_DIM * HID_DIM + k * HID_DIM + n])
                               : (unsigned short)0;
    }
    if (i < HID_DIM) {
        float s = 0.f;
        for (int e = 0; e < N_ETYPES; e++) s += b1[e * HID_DIM + i];
        b1s[i] = s;
    }
}

// ---------------- fused partition: hist + atomic range-reserve + scatter ---------
__global__ __launch_bounds__(256) void part_k(const int* __restrict__ src,
                                              const int* __restrict__ dst,
                                              int* __restrict__ gcur,
                                              unsigned* __restrict__ ep) {
    __shared__ int hist[NBKT];
    __shared__ int cur[NBKT];
    int e = blockIdx.y, blk = blockIdx.x, t = threadIdx.x;
    for (int b = t; b < NBKT; b += 256) hist[b] = 0;
    __syncthreads();
    const int* dp = dst + e * N_EDGES + blk * CHUNK;
    const int* sp = src + e * N_EDGES + blk * CHUNK;
    for (int k = t; k < CHUNK; k += 256) atomicAdd(&hist[dp[k] >> 8], 1);
    __syncthreads();
    for (int b = t; b < NBKT; b += 256)
        cur[b] = (hist[b] > 0) ? atomicAdd(&gcur[e * NBKT + b], hist[b]) : 0;
    __syncthreads();
    for (int k = t; k < CHUNK; k += 256) {
        int d = dp[k], s = sp[k];
        int b = d >> 8;
        int pos = atomicAdd(&cur[b], 1);
        if (pos < BKT_CAP)
            ep[(size_t)(e * NBKT + b) * BKT_CAP + pos] =
                (unsigned)s | ((unsigned)(d & 255) << 24);
    }
}

// ---------------- per-bucket counting sort -> node-sorted CSR + NOFF/DEG/INV ---
__global__ __launch_bounds__(256) void sort_k(const int* __restrict__ gcur,
                                              const unsigned* __restrict__ ep,
                                              unsigned* __restrict__ csr,
                                              int* __restrict__ noff,
                                              int* __restrict__ degn,
                                              float* __restrict__ inv) {
    __shared__ unsigned recs[BKT_CAP];
    __shared__ int hist[256];
    __shared__ int scn[256];
    __shared__ int curp[256];
    int b = blockIdx.x, e = blockIdx.y, t = threadIdx.x;
    int lin = e * NBKT + b;
    int S = lin * BKT_CAP;
    int cnt = gcur[lin];
    if (cnt > BKT_CAP) cnt = BKT_CAP;
    hist[t] = 0;
    __syncthreads();
    for (int i = t; i < cnt; i += 256) {
        unsigned r = ep[S + i];
        recs[i] = r;
        atomicAdd(&hist[r >> 24], 1);
    }
    __syncthreads();
    scn[t] = hist[t];
    __syncthreads();
    for (int o = 1; o < 256; o <<= 1) {
        int x = (t >= o) ? scn[t - o] : 0;
        __syncthreads();
        scn[t] += x;
        __syncthreads();
    }
    int excl = scn[t] - hist[t];
    curp[t] = excl;
    int n = b * 256 + t;
    if (n < N_NODES) {
        noff[e * N_NODES + n] = S + excl;
        degn[e * N_NODES + n] = hist[t];
        inv[e * N_NODES + n]  = 1.f / (float)(hist[t] + 1);
    }
    __syncthreads();
    for (int i = t; i < cnt; i += 256) {
        unsigned r = recs[i];
        int pos = atomicAdd(&curp[r >> 24], 1);
        csr[S + pos] = r & 0xFFFFFFu;
    }
}

// ---------------- fused agg1 + MLP (MFMA bf16) -----------------------------------
// Block = 64 nodes. Per etype: gather fp8 feat rows (CSR pull, register acc) straight
// into the LDS A-tile, stage W1^T, one MFMA round; after 5 etypes relu->H1s in LDS;
// phase 2 emits t2f8_e = fp8(H1 @ W2_e). AGG1B global round-trip eliminated.
__global__ __launch_bounds__(256) void gemm12_k(const int* __restrict__ noff,
                                                const int* __restrict__ degn,
                                                const float* __restrict__ inv,
                                                const unsigned* __restrict__ csr,
                                                const unsigned short* __restrict__ fb8,
                                                const unsigned short* __restrict__ w1tb,
                                                const float* __restrict__ b1s,
                                                const unsigned short* __restrict__ w2tb,
                                                unsigned char* __restrict__ t2f8) {
    __shared__ unsigned short H1s[64 * ASTR];   // 17.4 KB [node][k]
    __shared__ unsigned short Wt2[64 * ASTR];   // 17.4 KB; phase1 aliases:
    unsigned short* As1 = Wt2;                  //   [64*A1STR]  = 2560 ushorts
    unsigned short* Wt1 = Wt2 + 64 * A1STR;     //   [128*A1STR] = 5120 (7680 <= 8704 ok)
    int t = threadIdx.x;
    int node0 = blockIdx.x * 64;
    int w = t >> 6, lane = t & 63;
    int m = lane & 15, quad = lane >> 4;
    int glane = t & 15, grp = t >> 4;           // gather mapping: 16 groups x 16 lanes

    // ---- phase 1: H1 = relu(sum_e (gathered A_e) @ W1_e + b1s)
    f32x4 acc[8];
    for (int nt = 0; nt < 8; nt++) {
        float bb = b1s[nt * 16 + m];
        f32x4 c = {bb, bb, bb, bb};
        acc[nt] = c;
    }
    for (int e = 0; e < N_ETYPES; e++) {
        __syncthreads();                        // protect As1/Wt1 from prev MFMA readers
        // gather 64 rows of etype e into As1 (4 nodes per 16-lane group)
        for (int i = 0; i < 4; i++) {
            int nl = grp * 4 + i;
            int gn = node0 + nl;
            int cn = gn < N_NODES ? gn : N_NODES - 1;
            int idx = e * N_NODES + cn;
            int st = noff[idx];
            int cnt = degn[idx];
            float iv = inv[idx];
            f32x2 sv = __builtin_amdgcn_cvt_pk_f32_fp8((int)fb8[cn * 16 + glane], false);
            float a0 = sv.x, a1 = sv.y;
            int k = 0;
            for (; k + 3 < cnt; k += 4) {
                int s0 = csr[st + k];
                int s1 = csr[st + k + 1];
                int s2 = csr[st + k + 2];
                int s3 = csr[st + k + 3];
                f32x2 v0 = __builtin_amdgcn_cvt_pk_f32_fp8((int)fb8[s0 * 16 + glane], false);
                f32x2 v1 = __builtin_amdgcn_cvt_pk_f32_fp8((int)fb8[s1 * 16 + glane], false);
                f32x2 v2 = __builtin_amdgcn_cvt_pk_f32_fp8((int)fb8[s2 * 16 + glane], false);
                f32x2 v3 = __builtin_amdgcn_cvt_pk_f32_fp8((int)fb8[s3 * 16 + glane], false);
                a0 += (v0.x + v1.x) + (v2.x + v3.x);
                a1 += (v0.y + v1.y) + (v2.y + v3.y);
            }
            for (; k < cnt; k++) {
                int s0 = csr[st + k];
                f32x2 v0 = __builtin_amdgcn_cvt_pk_f32_fp8((int)fb8[s0 * 16 + glane], false);
                a0 += v0.x;
                a1 += v0.y;
            }
            ushort2 o; o.x = f2bf(a0 * iv); o.y = f2bf(a1 * iv);
            *(ushort2*)&As1[nl * A1STR + glane * 2] = o;
        }
        for (int j = t; j < 128 * 8; j += 256) {
            int n = j >> 3, c4 = (j & 7) * 4;
            *(ushort4*)&Wt1[n * A1STR + c4] =
                *(const ushort4*)&w1tb[(size_t)(e * HID_DIM + n) * 32 + c4];
        }
        __syncthreads();
        bf16x8 a = *(const bf16x8*)&As1[(w * 16 + m) * A1STR + quad * 8];
        for (int nt = 0; nt < 8; nt++) {
            bf16x8 b = *(const bf16x8*)&Wt1[(nt * 16 + m) * A1STR + quad * 8];
            acc[nt] = __builtin_amdgcn_mfma_f32_16x16x32_bf16(a, b, acc[nt], 0, 0, 0);
        }
    }
    __syncthreads();                           // done reading As1/Wt1 (aliases Wt2)
    for (int nt = 0; nt < 8; nt++)
        for (int r = 0; r < 4; r++)
            H1s[(w * 16 + quad * 4 + r) * ASTR + nt * 16 + m] =
                f2bf(fmaxf(acc[nt][r], 0.f));
    __syncthreads();

    // ---- phase 2: t2_e = fp8(H1 @ W2_e)
    bf16x8 a2[4];
    for (int ks = 0; ks < 4; ks++)
        a2[ks] = *(const bf16x8*)&H1s[(w * 16 + m) * ASTR + ks * 32 + quad * 8];
    for (int e = 0; e < N_ETYPES; e++) {
        __syncthreads();                       // protect Wt2 from prev readers
        for (int j = t; j < 64 * 32; j += 256) {
            int n = j >> 5, c4 = (j & 31) * 4;
            *(ushort4*)&Wt2[n * ASTR + c4] =
                *(const ushort4*)&w2tb[(e * OUT_DIM + n) * HID_DIM + c4];
        }
        __syncthreads();
        unsigned char* out = t2f8 + (size_t)e * N_NODES * OUT_DIM;
        for (int nt = 0; nt < 4; nt++) {
            f32x4 c = {0.f, 0.f, 0.f, 0.f};
            for (int ks = 0; ks < 4; ks++) {
                bf16x8 b = *(const bf16x8*)&Wt2[(nt * 16 + m) * ASTR + ks * 32 + quad * 8];
                c = __builtin_amdgcn_mfma_f32_16x16x32_bf16(a2[ks], b, c, 0, 0, 0);
            }
            for (int r = 0; r < 4; r++) {
                int gn = node0 + w * 16 + quad * 4 + r;
                if (gn < N_NODES) {
                    int p = __builtin_amdgcn_cvt_pk_fp8_f32(c[r], c[r], 0, false);
                    out[(size_t)gn * OUT_DIM + nt * 16 + m] = (unsigned char)(p & 0xFF);
                }
            }
        }
    }
}

// ---------------- layer2 pull + per-graph pool (r10-measured-best form) ----------
__global__ __launch_bounds__(256) void gather2_k(const int* __restrict__ noff,
                                                 const int* __restrict__ degn,
                                                 const float* __restrict__ inv,
                                                 const unsigned* __restrict__ csr,
                                                 const unsigned char* __restrict__ t2f8,
                                                 const int* __restrict__ gid,
                                                 float* __restrict__ gsum) {
    __shared__ float4 red4[16 * 4 * 16];    // 16 KB: [ng][slot][lane]
    int b = blockIdx.x, qb = blockIdx.y, t = threadIdx.x;
    int lane = t & 15, ng = t >> 4;
    int nbase = b * 256 + qb * 32;
    int gbase = nbase < N_NODES ? nbase : N_NODES - 1;
    int g0 = gid[gbase];
    float4 f[2];
    f[0] = make_float4(0.f, 0.f, 0.f, 0.f);
    f[1] = make_float4(0.f, 0.f, 0.f, 0.f);

    for (int e = 0; e < N_ETYPES; e++) {
        const unsigned char* base = t2f8 + (size_t)e * N_NODES * OUT_DIM;
        #pragma unroll
        for (int pass = 0; pass < 2; pass++) {
            int n = nbase + pass * 16 + ng;
            if (n >= N_NODES) break;
            int idx = e * N_NODES + n;
            int st = noff[idx];
            int cnt = degn[idx];
            float iv = inv[idx];
            unsigned rv = *(const unsigned*)&base[(size_t)n * OUT_DIM + lane * 4];
            f32x2 lo = __builtin_amdgcn_cvt_pk_f32_fp8((int)rv, false);
            f32x2 hi = __builtin_amdgcn_cvt_pk_f32_fp8((int)rv, true);
            float ax = lo.x, ay = lo.y, az = hi.x, aw = hi.y;
            int k = 0;
            for (; k + 3 < cnt; k += 4) {
                int sA = csr[st + k];
                int sB = csr[st + k + 1];
                int sC = csr[st + k + 2];
                int sD = csr[st + k + 3];
                unsigned rA = *(const unsigned*)&base[(size_t)sA * OUT_DIM + lane * 4];
                unsigned rB = *(const unsigned*)&base[(size_t)sB * OUT_DIM + lane * 4];
                unsigned rC = *(const unsigned*)&base[(size_t)sC * OUT_DIM + lane * 4];
                unsigned rD = *(const unsigned*)&base[(size_t)sD * OUT_DIM + lane * 4];
                f32x2 lA = __builtin_amdgcn_cvt_pk_f32_fp8((int)rA, false);
                f32x2 hA = __builtin_amdgcn_cvt_pk_f32_fp8((int)rA, true);
                f32x2 lB = __builtin_amdgcn_cvt_pk_f32_fp8((int)rB, false);
                f32x2 hB = __builtin_amdgcn_cvt_pk_f32_fp8((int)rB, true);
                f32x2 lC = __builtin_amdgcn_cvt_pk_f32_fp8((int)rC, false);
                f32x2 hC = __builtin_amdgcn_cvt_pk_f32_fp8((int)rC, true);
                f32x2 lD = __builtin_amdgcn_cvt_pk_f32_fp8((int)rD, false);
                f32x2 hD = __builtin_amdgcn_cvt_pk_f32_fp8((int)rD, true);
                ax += (lA.x + lB.x) + (lC.x + lD.x);
                ay += (lA.y + lB.y) + (lC.y + lD.y);
                az += (hA.x + hB.x) + (hC.x + hD.x);
                aw += (hA.y + hB.y) + (hC.y + hD.y);
            }
            for (; k < cnt; k++) {
                int sA = csr[st + k];
                unsigned rA = *(const unsigned*)&base[(size_t)sA * OUT_DIM + lane * 4];
                f32x2 lA = __builtin_amdgcn_cvt_pk_f32_fp8((int)rA, false);
                f32x2 hA = __builtin_amdgcn_cvt_pk_f32_fp8((int)rA, true);
                ax += lA.x; ay += lA.y; az += hA.x; aw += hA.y;
            }
            f[pass].x += iv * ax; f[pass].y += iv * ay;
            f[pass].z += iv * az; f[pass].w += iv * aw;
        }
    }

    float4 sa0 = {0,0,0,0}, sa1 = {0,0,0,0}, sa2 = {0,0,0,0}, sa3 = {0,0,0,0};
    #pragma unroll
    for (int pass = 0; pass < 2; pass++) {
        int n = nbase + pass * 16 + ng;
        if (n >= N_NODES) break;
        float4 v = f[pass];
        int slot = gid[n] - g0;
        float m0 = (slot == 0) ? 1.f : 0.f;
        float m1 = (slot == 1) ? 1.f : 0.f;
        float m2 = (slot == 2) ? 1.f : 0.f;
        float m3 = (slot == 3) ? 1.f : 0.f;
        sa0.x += m0 * v.x; sa0.y += m0 * v.y; sa0.z += m0 * v.z; sa0.w += m0 * v.w;
        sa1.x += m1 * v.x; sa1.y += m1 * v.y; sa1.z += m1 * v.z; sa1.w += m1 * v.w;
        sa2.x += m2 * v.x; sa2.y += m2 * v.y; sa2.z += m2 * v.z; sa2.w += m2 * v.w;
        sa3.x += m3 * v.x; sa3.y += m3 * v.y; sa3.z += m3 * v.z; sa3.w += m3 * v.w;
        if (slot > 3) {                      // statistically never
            atomicAdd(&gsum[(g0 + slot) * 64 + lane * 4 + 0], v.x);
            atomicAdd(&gsum[(g0 + slot) * 64 + lane * 4 + 1], v.y);
            atomicAdd(&gsum[(g0 + slot) * 64 + lane * 4 + 2], v.z);
            atomicAdd(&gsum[(g0 + slot) * 64 + lane * 4 + 3], v.w);
        }
    }
    red4[(ng * 4 + 0) * 16 + lane] = sa0;
    red4[(ng * 4 + 1) * 16 + lane] = sa1;
    red4[(ng * 4 + 2) * 16 + lane] = sa2;
    red4[(ng * 4 + 3) * 16 + lane] = sa3;
    __syncthreads();
    const float* red = (const float*)red4;
    int slot = t >> 6, d = t & 63;
    float s = 0.f;
    for (int j = 0; j < 16; j++) s += red[(j * 4 + slot) * 64 + d];
    int g = g0 + slot;
    if (g < NUM_GRAPHS) atomicAdd(&gsum[g * 64 + d], s);
}

// ---------------- per-graph node counts ----------------
__global__ __launch_bounds__(256) void gcnt_k(const int* __restrict__ gid,
                                              float* __restrict__ gcnt) {
    __shared__ int h[NUM_GRAPHS];
    int b = blockIdx.x, t = threadIdx.x;
    if (t < NUM_GRAPHS) h[t] = 0;
    __syncthreads();
    int n = b * 256 + t;
    if (n < N_NODES) atomicAdd(&h[gid[n]], 1);
    __syncthreads();
    if (t < NUM_GRAPHS && h[t] > 0) atomicAdd(&gcnt[t], (float)h[t]);
}

__global__ __launch_bounds__(256) void final_k(const float* __restrict__ gsum,
                                               const float* __restrict__ gcnt,
                                               const float* __restrict__ b2,
                                               float* __restrict__ out) {
    int idx = blockIdx.x * 256 + threadIdx.x;
    if (idx >= NUM_GRAPHS * OUT_DIM) return;
    int d = idx & 63;
    float B2 = 0.f;
    for (int e = 0; e < N_ETYPES; e++) B2 += b2[e * OUT_DIM + d];
    float c = gcnt[idx >> 6];
    out[idx] = (gsum[idx] + c * B2) / fmaxf(c, 1.0f);
}

extern "C" void kernel_launch(void* const* d_in, const int* in_sizes, int n_in,
                              void* d_out, int out_size, void* d_ws, size_t ws_size,
                              hipStream_t stream) {
    const float* feat = (const float*)d_in[0];
    const int*   src  = (const int*)d_in[1];
    const int*   dst  = (const int*)d_in[2];
    const int*   gid  = (const int*)d_in[3];
    const float* W1   = (const float*)d_in[4];
    const float* b1   = (const float*)d_in[5];
    const float* W2   = (const float*)d_in[6];
    const float* b2   = (const float*)d_in[7];

    float* ws = (float*)d_ws;
    int*            GCUR = (int*)ws;                         //   1,955 (pad 2,048)
    float*          INV  = ws + 2048;                        //   500,000
    int*            NOFF = (int*)ws + 502048;                //   500,000
    int*            DEGN = (int*)ws + 1002048;               //   500,000
    unsigned short* FB8  = (unsigned short*)(ws + 1502048);  //   1.6M ushort = 800,000 f
    float*          GSUM = ws + 2302048;                     //   4,096
    float*          GCNT = ws + 2306144;                     //   64
    unsigned*       EP   = (unsigned*)(ws + 2306208);        //   6,005,760 (slotted)
    unsigned*       CSR  = (unsigned*)(ws + 8311968);        //   6,005,760 (slotted)
    unsigned char*  T2F8 = (unsigned char*)(ws + 14317728);  //  32 MB = 8,000,000 f
    unsigned short* W1TB = (unsigned short*)(ws + 22317728); //  20,480 bf16 = 10,240 f
    unsigned short* W2TB = (unsigned short*)(ws + 22327968); //  40,960 bf16 = 20,480 f
    float*          B1S  = ws + 22348448;                    //   128
    // total 22,348,576 floats = 89.4 MB

    hipMemsetAsync(GCUR, 0, 2048 * sizeof(int), stream);
    hipMemsetAsync(GSUM, 0, (size_t)(4096 + 64) * sizeof(float), stream);

    cvt_feat_k<<<(N_NODES * 16 + 255) / 256, 256, 0, stream>>>(feat, FB8);
    cvt_w_k<<<(N_ETYPES * OUT_DIM * HID_DIM + 255) / 256, 256, 0, stream>>>(
        W1, b1, W2, W1TB, W2TB, B1S);
    part_k<<<dim3(PBLK, N_ETYPES), 256, 0, stream>>>(src, dst, GCUR, EP);
    sort_k<<<dim3(NBKT, N_ETYPES), 256, 0, stream>>>(GCUR, EP, CSR, NOFF, DEGN, INV);

    gemm12_k<<<(N_NODES + 63) / 64, 256, 0, stream>>>(NOFF, DEGN, INV, CSR, FB8,
                                                      W1TB, B1S, W2TB, T2F8);
    gather2_k<<<dim3(NBKT, 8), 256, 0, stream>>>(NOFF, DEGN, INV, CSR, T2F8, gid, GSUM);

    gcnt_k<<<391, 256, 0, stream>>>(gid, GCNT);
    final_k<<<16, 256, 0, stream>>>(GSUM, GCNT, b2, (float*)d_out);
}

// Round 15
// 363.483 us; speedup vs baseline: 1.1040x; 1.1040x over previous
//
#include <hip/hip_runtime.h>

#define N_NODES   100000
#define N_EDGES   800000
#define N_ETYPES  5
#define IN_DIM    23
#define HID_DIM   128
#define OUT_DIM   64
#define NUM_GRAPHS 64
#define NBKT      391                   // ceil(100000/256) dst buckets of 256 nodes
#define PBLK      125                   // partition blocks per etype
#define CHUNK     6400                  // 125*6400 = 800000 edges per etype
#define NB_E      (N_ETYPES*NBKT)       // 1955 (e,bucket) pairs
#define BKT_CAP   3072                  // slot size per (e,bucket); mean 2048 + 22 sigma
#define ASTR      136                   // gemm2-phase LDS stride: conflict-free b128 frags
#define A1STR     40                    // gemm1-phase LDS stride: 2-way only (free)

// NOTE (measured r3): bulk LDS float atomics ~3.5 cyc/lane on gfx950 — register acc only.
// NOTE (measured r6): unpadded bf16 LDS tiles -> 16-way conflicts on MFMA ds_read_b128.
// NOTE (measured r7-r11): random row-gather over a table >4MB/XCD has a compulsory
// L2-miss floor of 8 XCDs x touched-lines; tuning can't reduce it.
// NOTE (measured r12): pool-commute spool over 256 B H1 rows octupled edge payload — 4x
// regression. Pool-commute only pays if spooled rows are NARROWER than gathered rows.
// NOTE (measured r5/r10/r13): row-gather kernels are bound by the vector-memory
// transaction rate: ~13 cyc per distinct line per CU (~50k lines/us device-wide),
// independent of row bytes. Floor per gather stage = edge_count / 50k ~ 85-90 us.
// NOTE (measured r14): fusing the latency-bound gather into the barrier-phased MFMA
// kernel regressed 385.7->401.3 (gather needs free-running waves at high block count;
// barriers make block time = max over groups). Gather stages stay standalone.

__device__ __forceinline__ unsigned short f2bf(float x) {
    unsigned u = __float_as_uint(x);
    unsigned r = (u + 0x7FFFu + ((u >> 16) & 1u)) >> 16;   // RNE
    return (unsigned short)r;
}
__device__ __forceinline__ float bf2f(unsigned short h) {
    return __uint_as_float(((unsigned)h) << 16);
}

typedef __attribute__((ext_vector_type(8))) short bf16x8;
typedef __attribute__((ext_vector_type(4))) float f32x4;
typedef __attribute__((ext_vector_type(2))) float f32x2;

// ---------------- merged prep: feat->fp8 table, W1^T bf16, W2^T bf16, b1 sum -----
__global__ __launch_bounds__(256) void cvt_k(const float* __restrict__ feat,
                                             const float* __restrict__ W1,
                                             const float* __restrict__ b1,
                                             const float* __restrict__ W2,
                                             unsigned short* __restrict__ fb8,
                                             unsigned short* __restrict__ w1tb,
                                             unsigned short* __restrict__ w2tb,
                                             float* __restrict__ b1s) {
    int i = blockIdx.x * 256 + threadIdx.x;
    if (i < N_NODES * 16) {
        int n = i >> 4, p = i & 15;
        int d0 = p * 2, d1 = d0 + 1;
        float f0 = (d0 < IN_DIM) ? feat[n * IN_DIM + d0] : 0.f;
        float f1 = (d1 < IN_DIM) ? feat[n * IN_DIM + d1] : 0.f;
        int pk = __builtin_amdgcn_cvt_pk_fp8_f32(f0, f1, 0, false);
        fb8[i] = (unsigned short)(pk & 0xFFFF);
    }
    if (i < N_ETYPES * OUT_DIM * HID_DIM) {
        int e = i / (OUT_DIM * HID_DIM);
        int r = i - e * (OUT_DIM * HID_DIM);
        int n = r >> 7, k = r & 127;
        w2tb[i] = f2bf(W2[(e * HID_DIM + k) * OUT_DIM + n]);
    }
    if (i < N_ETYPES * HID_DIM * 32) {
        int e = i / (HID_DIM * 32);
        int r = i - e * (HID_DIM * 32);
        int n = r >> 5, k = r & 31;
        w1tb[i] = (k < IN_DIM) ? f2bf(W1[e * IN_DIM * HID_DIM + k * HID_DIM + n])
                               : (unsigned short)0;
    }
    if (i < HID_DIM) {
        float s = 0.f;
        for (int e = 0; e < N_ETYPES; e++) s += b1[e * HID_DIM + i];
        b1s[i] = s;
    }
}

// ---------------- fused partition: hist + atomic range-reserve + scatter ---------
__global__ __launch_bounds__(256) void part_k(const int* __restrict__ src,
                                              const int* __restrict__ dst,
                                              int* __restrict__ gcur,
                                              unsigned* __restrict__ ep) {
    __shared__ int hist[NBKT];
    __shared__ int cur[NBKT];
    int e = blockIdx.y, blk = blockIdx.x, t = threadIdx.x;
    for (int b = t; b < NBKT; b += 256) hist[b] = 0;
    __syncthreads();
    const int* dp = dst + e * N_EDGES + blk * CHUNK;
    const int* sp = src + e * N_EDGES + blk * CHUNK;
    for (int k = t; k < CHUNK; k += 256) atomicAdd(&hist[dp[k] >> 8], 1);
    __syncthreads();
    for (int b = t; b < NBKT; b += 256)
        cur[b] = (hist[b] > 0) ? atomicAdd(&gcur[e * NBKT + b], hist[b]) : 0;
    __syncthreads();
    for (int k = t; k < CHUNK; k += 256) {
        int d = dp[k], s = sp[k];
        int b = d >> 8;
        int pos = atomicAdd(&cur[b], 1);
        if (pos < BKT_CAP)
            ep[(size_t)(e * NBKT + b) * BKT_CAP + pos] =
                (unsigned)s | ((unsigned)(d & 255) << 24);
    }
}

// ---------------- fused sort + layer1 aggregate ----------------------------------
// Block = one (e,bucket) = 256 dst nodes. LDS counting-sort records by node local
// idx; emit CSR/NOFF/DEGN/INV for gather2; then aggregate fp8 feat rows directly
// from the LDS-sorted list (free-running gather, no barriers after sort phase).
__global__ __launch_bounds__(256) void aggsort_k(const int* __restrict__ gcur,
                                                 const unsigned* __restrict__ ep,
                                                 unsigned* __restrict__ csr,
                                                 int* __restrict__ noff,
                                                 int* __restrict__ degn,
                                                 float* __restrict__ inv,
                                                 const unsigned short* __restrict__ fb8,
                                                 unsigned short* __restrict__ agg1b) {
    __shared__ unsigned recs[BKT_CAP];
    __shared__ unsigned srt[BKT_CAP];
    __shared__ int hist[256];
    __shared__ int scn[256];
    __shared__ int curp[256];
    __shared__ int boffl[256];
    __shared__ float invl[256];
    int b = blockIdx.x, e = blockIdx.y, t = threadIdx.x;
    int lin = e * NBKT + b;
    int S = lin * BKT_CAP;
    int cnt = gcur[lin];
    if (cnt > BKT_CAP) cnt = BKT_CAP;
    hist[t] = 0;
    __syncthreads();
    for (int i = t; i < cnt; i += 256) {
        unsigned r = ep[S + i];
        recs[i] = r;
        atomicAdd(&hist[r >> 24], 1);
    }
    __syncthreads();
    scn[t] = hist[t];
    __syncthreads();
    for (int o = 1; o < 256; o <<= 1) {
        int x = (t >= o) ? scn[t - o] : 0;
        __syncthreads();
        scn[t] += x;
        __syncthreads();
    }
    int excl = scn[t] - hist[t];
    curp[t] = excl;
    boffl[t] = excl;
    float iv = 1.f / (float)(hist[t] + 1);
    invl[t] = iv;
    int n = b * 256 + t;
    if (n < N_NODES) {
        noff[e * N_NODES + n] = S + excl;
        degn[e * N_NODES + n] = hist[t];
        inv[e * N_NODES + n]  = iv;
    }
    __syncthreads();
    for (int i = t; i < cnt; i += 256) {
        unsigned r = recs[i];
        int pos = atomicAdd(&curp[r >> 24], 1);
        srt[pos] = r & 0xFFFFFFu;
    }
    __syncthreads();
    // CSR out (coalesced) for gather2
    for (int i = t; i < cnt; i += 256) csr[S + i] = srt[i];

    // aggregate: 16 groups x 16 lanes; lists read from LDS, rows from fb8 (L2-hot)
    int glane = t & 15, grp = t >> 4;
    for (int pass = 0; pass < 16; pass++) {
        int nl = pass * 16 + grp;
        int gn = b * 256 + nl;
        int cn = gn < N_NODES ? gn : N_NODES - 1;
        int st = boffl[nl];
        int dn = hist[nl];
        f32x2 sv = __builtin_amdgcn_cvt_pk_f32_fp8((int)fb8[cn * 16 + glane], false);
        float a0 = sv.x, a1 = sv.y;
        int k = 0;
        for (; k + 3 < dn; k += 4) {
            int s0 = srt[st + k];
            int s1 = srt[st + k + 1];
            int s2 = srt[st + k + 2];
            int s3 = srt[st + k + 3];
            f32x2 v0 = __builtin_amdgcn_cvt_pk_f32_fp8((int)fb8[s0 * 16 + glane], false);
            f32x2 v1 = __builtin_amdgcn_cvt_pk_f32_fp8((int)fb8[s1 * 16 + glane], false);
            f32x2 v2 = __builtin_amdgcn_cvt_pk_f32_fp8((int)fb8[s2 * 16 + glane], false);
            f32x2 v3 = __builtin_amdgcn_cvt_pk_f32_fp8((int)fb8[s3 * 16 + glane], false);
            a0 += (v0.x + v1.x) + (v2.x + v3.x);
            a1 += (v0.y + v1.y) + (v2.y + v3.y);
        }
        for (; k < dn; k++) {
            int s0 = srt[st + k];
            f32x2 v0 = __builtin_amdgcn_cvt_pk_f32_fp8((int)fb8[s0 * 16 + glane], false);
            a0 += v0.x;
            a1 += v0.y;
        }
        if (gn < N_NODES) {
            float ivv = invl[nl];
            ushort2 o; o.x = f2bf(a0 * ivv); o.y = f2bf(a1 * ivv);
            *(ushort2*)&agg1b[(size_t)(e * N_NODES + gn) * 32 + glane * 2] = o;
        }
    }
}

// ---------------- fused MLP (MFMA bf16): H1 in LDS, t2f8_e = fp8(H1 @ W2_e) ------
__global__ __launch_bounds__(256) void gemm12_k(const unsigned short* __restrict__ agg1b,
                                                const unsigned short* __restrict__ w1tb,
                                                const float* __restrict__ b1s,
                                                const unsigned short* __restrict__ w2tb,
                                                unsigned char* __restrict__ t2f8) {
    __shared__ unsigned short H1s[64 * ASTR];   // 17.4 KB [node][k]
    __shared__ unsigned short Wt2[64 * ASTR];   // 17.4 KB; phase1 aliases:
    unsigned short* As1 = Wt2;                  //   [64*A1STR]  = 2560 ushorts
    unsigned short* Wt1 = Wt2 + 64 * A1STR;     //   [128*A1STR] = 5120 (7680 <= 8704 ok)
    int t = threadIdx.x;
    int node0 = blockIdx.x * 64;
    int w = t >> 6, lane = t & 63;
    int m = lane & 15, quad = lane >> 4;

    // ---- phase 1: H1 = relu(sum_e A_e @ W1_e + b1s)
    f32x4 acc[8];
    for (int nt = 0; nt < 8; nt++) {
        float bb = b1s[nt * 16 + m];
        f32x4 c = {bb, bb, bb, bb};
        acc[nt] = c;
    }
    for (int e = 0; e < N_ETYPES; e++) {
        __syncthreads();
        for (int j = t; j < 64 * 8; j += 256) {
            int n = j >> 3, c4 = (j & 7) * 4;
            int gn = node0 + n;
            int cn = gn < N_NODES ? gn : N_NODES - 1;
            *(ushort4*)&As1[n * A1STR + c4] =
                *(const ushort4*)&agg1b[(size_t)(e * N_NODES + cn) * 32 + c4];
        }
        for (int j = t; j < 128 * 8; j += 256) {
            int n = j >> 3, c4 = (j & 7) * 4;
            *(ushort4*)&Wt1[n * A1STR + c4] =
                *(const ushort4*)&w1tb[(size_t)(e * HID_DIM + n) * 32 + c4];
        }
        __syncthreads();
        bf16x8 a = *(const bf16x8*)&As1[(w * 16 + m) * A1STR + quad * 8];
        for (int nt = 0; nt < 8; nt++) {
            bf16x8 b = *(const bf16x8*)&Wt1[(nt * 16 + m) * A1STR + quad * 8];
            acc[nt] = __builtin_amdgcn_mfma_f32_16x16x32_bf16(a, b, acc[nt], 0, 0, 0);
        }
    }
    __syncthreads();                           // done reading As1/Wt1 (aliases Wt2)
    for (int nt = 0; nt < 8; nt++)
        for (int r = 0; r < 4; r++)
            H1s[(w * 16 + quad * 4 + r) * ASTR + nt * 16 + m] =
                f2bf(fmaxf(acc[nt][r], 0.f));
    __syncthreads();

    // ---- phase 2: t2_e = fp8(H1 @ W2_e)
    bf16x8 a2[4];
    for (int ks = 0; ks < 4; ks++)
        a2[ks] = *(const bf16x8*)&H1s[(w * 16 + m) * ASTR + ks * 32 + quad * 8];
    for (int e = 0; e < N_ETYPES; e++) {
        __syncthreads();                       // protect Wt2 from prev readers
        for (int j = t; j < 64 * 32; j += 256) {
            int n = j >> 5, c4 = (j & 31) * 4;
            *(ushort4*)&Wt2[n * ASTR + c4] =
                *(const ushort4*)&w2tb[(e * OUT_DIM + n) * HID_DIM + c4];
        }
        __syncthreads();
        unsigned char* out = t2f8 + (size_t)e * N_NODES * OUT_DIM;
        for (int nt = 0; nt < 4; nt++) {
            f32x4 c = {0.f, 0.f, 0.f, 0.f};
            for (int ks = 0; ks < 4; ks++) {
                bf16x8 b = *(const bf16x8*)&Wt2[(nt * 16 + m) * ASTR + ks * 32 + quad * 8];
                c = __builtin_amdgcn_mfma_f32_16x16x32_bf16(a2[ks], b, c, 0, 0, 0);
            }
            for (int r = 0; r < 4; r++) {
                int gn = node0 + w * 16 + quad * 4 + r;
                if (gn < N_NODES) {
                    int p = __builtin_amdgcn_cvt_pk_fp8_f32(c[r], c[r], 0, false);
                    out[(size_t)gn * OUT_DIM + nt * 16 + m] = (unsigned char)(p & 0xFF);
                }
            }
        }
    }
}

// ---------------- layer2 pull + per-graph pool (r10-measured-best form) ----------
__global__ __launch_bounds__(256) void gather2_k(const int* __restrict__ noff,
                                                 const int* __restrict__ degn,
                                                 const float* __restrict__ inv,
                                                 const unsigned* __restrict__ csr,
                                                 const unsigned char* __restrict__ t2f8,
                                                 const int* __restrict__ gid,
                                                 float* __restrict__ gsum) {
    __shared__ float4 red4[16 * 4 * 16];    // 16 KB: [ng][slot][lane]
    int b = blockIdx.x, qb = blockIdx.y, t = threadIdx.x;
    int lane = t & 15, ng = t >> 4;
    int nbase = b * 256 + qb * 32;
    int gbase = nbase < N_NODES ? nbase : N_NODES - 1;
    int g0 = gid[gbase];
    float4 f[2];
    f[0] = make_float4(0.f, 0.f, 0.f, 0.f);
    f[1] = make_float4(0.f, 0.f, 0.f, 0.f);

    for (int e = 0; e < N_ETYPES; e++) {
        const unsigned char* base = t2f8 + (size_t)e * N_NODES * OUT_DIM;
        #pragma unroll
        for (int pass = 0; pass < 2; pass++) {
            int n = nbase + pass * 16 + ng;
            if (n >= N_NODES) break;
            int idx = e * N_NODES + n;
            int st = noff[idx];
            int cnt = degn[idx];
            float iv = inv[idx];
            unsigned rv = *(const unsigned*)&base[(size_t)n * OUT_DIM + lane * 4];
            f32x2 lo = __builtin_amdgcn_cvt_pk_f32_fp8((int)rv, false);
            f32x2 hi = __builtin_amdgcn_cvt_pk_f32_fp8((int)rv, true);
            float ax = lo.x, ay = lo.y, az = hi.x, aw = hi.y;
            int k = 0;
            for (; k + 3 < cnt; k += 4) {
                int sA = csr[st + k];
                int sB = csr[st + k + 1];
                int sC = csr[st + k + 2];
                int sD = csr[st + k + 3];
                unsigned rA = *(const unsigned*)&base[(size_t)sA * OUT_DIM + lane * 4];
                unsigned rB = *(const unsigned*)&base[(size_t)sB * OUT_DIM + lane * 4];
                unsigned rC = *(const unsigned*)&base[(size_t)sC * OUT_DIM + lane * 4];
                unsigned rD = *(const unsigned*)&base[(size_t)sD * OUT_DIM + lane * 4];
                f32x2 lA = __builtin_amdgcn_cvt_pk_f32_fp8((int)rA, false);
                f32x2 hA = __builtin_amdgcn_cvt_pk_f32_fp8((int)rA, true);
                f32x2 lB = __builtin_amdgcn_cvt_pk_f32_fp8((int)rB, false);
                f32x2 hB = __builtin_amdgcn_cvt_pk_f32_fp8((int)rB, true);
                f32x2 lC = __builtin_amdgcn_cvt_pk_f32_fp8((int)rC, false);
                f32x2 hC = __builtin_amdgcn_cvt_pk_f32_fp8((int)rC, true);
                f32x2 lD = __builtin_amdgcn_cvt_pk_f32_fp8((int)rD, false);
                f32x2 hD = __builtin_amdgcn_cvt_pk_f32_fp8((int)rD, true);
                ax += (lA.x + lB.x) + (lC.x + lD.x);
                ay += (lA.y + lB.y) + (lC.y + lD.y);
                az += (hA.x + hB.x) + (hC.x + hD.x);
                aw += (hA.y + hB.y) + (hC.y + hD.y);
            }
            for (; k < cnt; k++) {
                int sA = csr[st + k];
                unsigned rA = *(const unsigned*)&base[(size_t)sA * OUT_DIM + lane * 4];
                f32x2 lA = __builtin_amdgcn_cvt_pk_f32_fp8((int)rA, false);
                f32x2 hA = __builtin_amdgcn_cvt_pk_f32_fp8((int)rA, true);
                ax += lA.x; ay += lA.y; az += hA.x; aw += hA.y;
            }
            f[pass].x += iv * ax; f[pass].y += iv * ay;
            f[pass].z += iv * az; f[pass].w += iv * aw;
        }
    }

    float4 sa0 = {0,0,0,0}, sa1 = {0,0,0,0}, sa2 = {0,0,0,0}, sa3 = {0,0,0,0};
    #pragma unroll
    for (int pass = 0; pass < 2; pass++) {
        int n = nbase + pass * 16 + ng;
        if (n >= N_NODES) break;
        float4 v = f[pass];
        int slot = gid[n] - g0;
        float m0 = (slot == 0) ? 1.f : 0.f;
        float m1 = (slot == 1) ? 1.f : 0.f;
        float m2 = (slot == 2) ? 1.f : 0.f;
        float m3 = (slot == 3) ? 1.f : 0.f;
        sa0.x += m0 * v.x; sa0.y += m0 * v.y; sa0.z += m0 * v.z; sa0.w += m0 * v.w;
        sa1.x += m1 * v.x; sa1.y += m1 * v.y; sa1.z += m1 * v.z; sa1.w += m1 * v.w;
        sa2.x += m2 * v.x; sa2.y += m2 * v.y; sa2.z += m2 * v.z; sa2.w += m2 * v.w;
        sa3.x += m3 * v.x; sa3.y += m3 * v.y; sa3.z += m3 * v.z; sa3.w += m3 * v.w;
        if (slot > 3) {                      // statistically never
            atomicAdd(&gsum[(g0 + slot) * 64 + lane * 4 + 0], v.x);
            atomicAdd(&gsum[(g0 + slot) * 64 + lane * 4 + 1], v.y);
            atomicAdd(&gsum[(g0 + slot) * 64 + lane * 4 + 2], v.z);
            atomicAdd(&gsum[(g0 + slot) * 64 + lane * 4 + 3], v.w);
        }
    }
    red4[(ng * 4 + 0) * 16 + lane] = sa0;
    red4[(ng * 4 + 1) * 16 + lane] = sa1;
    red4[(ng * 4 + 2) * 16 + lane] = sa2;
    red4[(ng * 4 + 3) * 16 + lane] = sa3;
    __syncthreads();
    const float* red = (const float*)red4;
    int slot = t >> 6, d = t & 63;
    float s = 0.f;
    for (int j = 0; j < 16; j++) s += red[(j * 4 + slot) * 64 + d];
    int g = g0 + slot;
    if (g < NUM_GRAPHS) atomicAdd(&gsum[g * 64 + d], s);
}

// ---------------- per-graph node counts ----------------
__global__ __launch_bounds__(256) void gcnt_k(const int* __restrict__ gid,
                                              float* __restrict__ gcnt) {
    __shared__ int h[NUM_GRAPHS];
    int b = blockIdx.x, t = threadIdx.x;
    if (t < NUM_GRAPHS) h[t] = 0;
    __syncthreads();
    int n = b * 256 + t;
    if (n < N_NODES) atomicAdd(&h[gid[n]], 1);
    __syncthreads();
    if (t < NUM_GRAPHS && h[t] > 0) atomicAdd(&gcnt[t], (float)h[t]);
}

__global__ __launch_bounds__(256) void final_k(const float* __restrict__ gsum,
                                               const float* __restrict__ gcnt,
                                               const float* __restrict__ b2,
                                               float* __restrict__ out) {
    int idx = blockIdx.x * 256 + threadIdx.x;
    if (idx >= NUM_GRAPHS * OUT_DIM) return;
    int d = idx & 63;
    float B2 = 0.f;
    for (int e = 0; e < N_ETYPES; e++) B2 += b2[e * OUT_DIM + d];
    float c = gcnt[idx >> 6];
    out[idx] = (gsum[idx] + c * B2) / fmaxf(c, 1.0f);
}

extern "C" void kernel_launch(void* const* d_in, const int* in_sizes, int n_in,
                              void* d_out, int out_size, void* d_ws, size_t ws_size,
                              hipStream_t stream) {
    const float* feat = (const float*)d_in[0];
    const int*   src  = (const int*)d_in[1];
    const int*   dst  = (const int*)d_in[2];
    const int*   gid  = (const int*)d_in[3];
    const float* W1   = (const float*)d_in[4];
    const float* b1   = (const float*)d_in[5];
    const float* W2   = (const float*)d_in[6];
    const float* b2   = (const float*)d_in[7];

    float* ws = (float*)d_ws;
    int*            GCUR = (int*)ws;                         //   1,955 (pad 2,048)
    float*          INV  = ws + 2048;                        //   500,000
    int*            NOFF = (int*)ws + 502048;                //   500,000
    int*            DEGN = (int*)ws + 1002048;               //   500,000
    unsigned short* FB8  = (unsigned short*)(ws + 1502048);  //   1.6M ushort = 800,000 f
    float*          GSUM = ws + 2302048;                     //   4,096
    float*          GCNT = ws + 2306144;                     //   64
    unsigned*       EP   = (unsigned*)(ws + 2306208);        //   6,005,760 (slotted)
    unsigned*       CSR  = (unsigned*)(ws + 8311968);        //   6,005,760 (slotted)
    unsigned short* AGG1B= (unsigned short*)(ws + 14317728); //  16M bf16 = 8,000,000 f
    unsigned char*  T2F8 = (unsigned char*)(ws + 22317728);  //  32 MB = 8,000,000 f
    unsigned short* W1TB = (unsigned short*)(ws + 30317728); //  20,480 bf16 = 10,240 f
    unsigned short* W2TB = (unsigned short*)(ws + 30327968); //  40,960 bf16 = 20,480 f
    float*          B1S  = ws + 30348448;                    //   128
    // total 30,348,576 floats = 121.4 MB

    hipMemsetAsync(GCUR, 0, 2048 * sizeof(int), stream);
    hipMemsetAsync(GSUM, 0, (size_t)(4096 + 64) * sizeof(float), stream);

    cvt_k<<<(N_NODES * 16 + 255) / 256, 256, 0, stream>>>(feat, W1, b1, W2,
                                                          FB8, W1TB, W2TB, B1S);
    part_k<<<dim3(PBLK, N_ETYPES), 256, 0, stream>>>(src, dst, GCUR, EP);
    aggsort_k<<<dim3(NBKT, N_ETYPES), 256, 0, stream>>>(GCUR, EP, CSR, NOFF, DEGN,
                                                        INV, FB8, AGG1B);
    gemm12_k<<<(N_NODES + 63) / 64, 256, 0, stream>>>(AGG1B, W1TB, B1S, W2TB, T2F8);
    gather2_k<<<dim3(NBKT, 8), 256, 0, stream>>>(NOFF, DEGN, INV, CSR, T2F8, gid, GSUM);

    gcnt_k<<<391, 256, 0, stream>>>(gid, GCNT);
    final_k<<<16, 256, 0, stream>>>(GSUM, GCNT, b2, (float*)d_out);
}